// Round 6
// baseline (641.036 us; speedup 1.0000x reference)
//
#include <hip/hip_runtime.h>
#include <hip/hip_fp16.h>

#define NN 50000
#define NE 200000
#define IND 512
#define HIDD 2000
#define LATD 128

#define M_PAD 50176    // 784*64
#define N1_PAD 2048    // HIDD padded (pad cols forced to exact 0)
#define NBLK 196       // ceil(NN/256)

typedef _Float16 f16x8 __attribute__((ext_vector_type(8)));
typedef float f32x4 __attribute__((ext_vector_type(4)));

__device__ __forceinline__ void gload_lds16(const _Float16* g, _Float16* l) {
    __builtin_amdgcn_global_load_lds(
        (const __attribute__((address_space(1))) unsigned int*)g,
        (__attribute__((address_space(3))) unsigned int*)l,
        16, 0, 0);
}

// ---- in-degree (int): deg[col[e]] += 1 ----
__global__ void k_degree(const int* __restrict__ col, int* __restrict__ deg) {
    int e = blockIdx.x * 256 + threadIdx.x;
    if (e < NE) atomicAdd(&deg[col[e]], 1);
}

// ---- hierarchical exclusive scan: (1) per-block sums ----
__global__ void k_bsum(const int* __restrict__ deg, int* __restrict__ bsum) {
    __shared__ int sm[4];
    int i = blockIdx.x * 256 + threadIdx.x;
    int v = (i < NN) ? deg[i] : 0;
    #pragma unroll
    for (int off = 32; off; off >>= 1) v += __shfl_down(v, off, 64);
    if ((threadIdx.x & 63) == 0) sm[threadIdx.x >> 6] = v;
    __syncthreads();
    if (threadIdx.x == 0) bsum[blockIdx.x] = sm[0] + sm[1] + sm[2] + sm[3];
}

// ---- (2) exclusive scan of the 196 block sums (one block) ----
__global__ void k_bscan(int* __restrict__ bsum) {
    __shared__ int sm[256];
    int tid = threadIdx.x;
    int v = (tid < NBLK) ? bsum[tid] : 0;
    sm[tid] = v;
    __syncthreads();
    #pragma unroll
    for (int off = 1; off < 256; off <<= 1) {
        int t = (tid >= off) ? sm[tid - off] : 0;
        __syncthreads();
        sm[tid] += t;
        __syncthreads();
    }
    if (tid < NBLK) bsum[tid] = sm[tid] - v;   // exclusive
}

// ---- (3) per-block exclusive scan + offset -> row_ptr; also dis = rsqrt(deg+1) ----
__global__ void k_scan_final(const int* __restrict__ deg, const int* __restrict__ bsum,
                             int* __restrict__ row_ptr, float* __restrict__ dis) {
    __shared__ int sm[256];
    int b = blockIdx.x, tid = threadIdx.x;
    int i = b * 256 + tid;
    int v = (i < NN) ? deg[i] : 0;
    if (i < NN) dis[i] = rsqrtf((float)v + 1.0f);
    sm[tid] = v;
    __syncthreads();
    #pragma unroll
    for (int off = 1; off < 256; off <<= 1) {
        int t = (tid >= off) ? sm[tid - off] : 0;
        __syncthreads();
        sm[tid] += t;
        __syncthreads();
    }
    if (i < NN) row_ptr[i] = bsum[b] + sm[tid] - v;
    if (i == NN - 1) row_ptr[NN] = bsum[b] + sm[tid];
}

// ---- fill CSR: csr_src[row_ptr[c] + cursor[c]++] = r ----
__global__ void k_fill(const int* __restrict__ ei, const int* __restrict__ row_ptr,
                       int* __restrict__ cursor, int* __restrict__ csr_src) {
    int e = blockIdx.x * 256 + threadIdx.x;
    if (e < NE) {
        int r = ei[e], c = ei[NE + e];
        int pos = atomicAdd(&cursor[c], 1);
        csr_src[row_ptr[c] + pos] = r;
    }
}

// ---- LDS-tiled transpose+convert: in f32 [R][C] -> out fp16, out[c*ldo + r].
//      Writes the FULL padded range, zero-filling pads (no separate memset). ----
__global__ void k_transpose_tiled(const float* __restrict__ in,
                                  _Float16* __restrict__ out, int R, int C, int ldo,
                                  int Rpad, int Cpad) {
    __shared__ float sm[32][33];
    int c0 = blockIdx.x * 32, r0 = blockIdx.y * 32;
    int tx = threadIdx.x & 31, ty = threadIdx.x >> 5;   // 32 x 8
    #pragma unroll
    for (int i = 0; i < 4; ++i) {
        int r = r0 + ty + i * 8, c = c0 + tx;
        sm[ty + i * 8][tx] = (r < R && c < C) ? in[(size_t)r * C + c] : 0.f;
    }
    __syncthreads();
    #pragma unroll
    for (int i = 0; i < 4; ++i) {
        int c = c0 + ty + i * 8, r = r0 + tx;
        if (c < Cpad && r < Rpad) out[(size_t)c * ldo + r] = (_Float16)sm[tx][ty + i * 8];
    }
}

// ---- x f32 -> xh fp16 (8 elems/thread) ----
__global__ void k_xcvt(const float* __restrict__ in, _Float16* __restrict__ out, int n8) {
    int i = blockIdx.x * 256 + threadIdx.x;
    if (i < n8) {
        float4 a = ((const float4*)in)[i * 2];
        float4 b = ((const float4*)in)[i * 2 + 1];
        f16x8 o;
        o[0] = (_Float16)a.x; o[1] = (_Float16)a.y; o[2] = (_Float16)a.z; o[3] = (_Float16)a.w;
        o[4] = (_Float16)b.x; o[5] = (_Float16)b.y; o[6] = (_Float16)b.z; o[7] = (_Float16)b.w;
        ((f16x8*)out)[i] = o;
    }
}

// ---- gather-aggregate x (fp16 src), 4-wide independent load slots ----
__global__ void k_gather_x(const _Float16* __restrict__ xh, const int* __restrict__ row_ptr,
                           const int* __restrict__ csr_src, const float* __restrict__ dis,
                           _Float16* __restrict__ Ah) {
    int dst = blockIdx.x * 4 + (threadIdx.x >> 6);
    if (dst >= NN) return;
    int lane = threadIdx.x & 63;
    float dd = dis[dst];
    const f16x8* vb = (const f16x8*)xh;                 // node stride 64 (512 halves / 8)
    f16x8 sv = vb[(size_t)dst * 64 + lane];
    float acc[8];
    #pragma unroll
    for (int q = 0; q < 8; ++q) acc[q] = dd * (float)sv[q];
    int beg = row_ptr[dst], end = row_ptr[dst + 1];
    for (int c = beg; c < end; c += 64) {
        int n = end - c; if (n > 64) n = 64;
        int li = (lane < n) ? csr_src[c + lane] : 0;    // lane-parallel idx load
        float lns = (lane < n) ? dis[li] : 0.f;         // lane-parallel dis gather
        for (int j = 0; j < n; j += 4) {
            int j1 = j + 1 < n ? j + 1 : n - 1;
            int j2 = j + 2 < n ? j + 2 : n - 1;
            int j3 = j + 3 < n ? j + 3 : n - 1;
            int s0 = __shfl(li, j),  s1 = __shfl(li, j1);
            int s2 = __shfl(li, j2), s3 = __shfl(li, j3);
            float w0 = __shfl(lns, j);
            float w1 = (j + 1 < n) ? __shfl(lns, j1) : 0.f;
            float w2 = (j + 2 < n) ? __shfl(lns, j2) : 0.f;
            float w3 = (j + 3 < n) ? __shfl(lns, j3) : 0.f;
            f16x8 v0 = vb[(size_t)s0 * 64 + lane];
            f16x8 v1 = vb[(size_t)s1 * 64 + lane];
            f16x8 v2 = vb[(size_t)s2 * 64 + lane];
            f16x8 v3 = vb[(size_t)s3 * 64 + lane];
            #pragma unroll
            for (int q = 0; q < 8; ++q)
                acc[q] += w0 * (float)v0[q] + w1 * (float)v1[q]
                        + w2 * (float)v2[q] + w3 * (float)v3[q];
        }
    }
    f16x8 o;
    #pragma unroll
    for (int q = 0; q < 8; ++q) o[q] = (_Float16)(dd * acc[q]);
    *(f16x8*)(Ah + (size_t)dst * IND + lane * 8) = o;
}

// ---- gather-aggregate t + bias + sigmoid -> out (f32), same 4-wide slots ----
__global__ void k_gather_t(const float* __restrict__ t, const int* __restrict__ row_ptr,
                           const int* __restrict__ csr_src, const float* __restrict__ dis,
                           const float* __restrict__ b2, float* __restrict__ out) {
    int dst = blockIdx.x * 4 + (threadIdx.x >> 6);
    if (dst >= NN) return;
    int lane = threadIdx.x & 63;
    float dd = dis[dst];
    const float2* vb = (const float2*)t;                // node stride 64 (128 f32 / 2)
    float2 td = vb[(size_t)dst * 64 + lane];
    float accx = dd * td.x, accy = dd * td.y;
    int beg = row_ptr[dst], end = row_ptr[dst + 1];
    for (int c = beg; c < end; c += 64) {
        int n = end - c; if (n > 64) n = 64;
        int li = (lane < n) ? csr_src[c + lane] : 0;
        float lns = (lane < n) ? dis[li] : 0.f;
        for (int j = 0; j < n; j += 4) {
            int j1 = j + 1 < n ? j + 1 : n - 1;
            int j2 = j + 2 < n ? j + 2 : n - 1;
            int j3 = j + 3 < n ? j + 3 : n - 1;
            int s0 = __shfl(li, j),  s1 = __shfl(li, j1);
            int s2 = __shfl(li, j2), s3 = __shfl(li, j3);
            float w0 = __shfl(lns, j);
            float w1 = (j + 1 < n) ? __shfl(lns, j1) : 0.f;
            float w2 = (j + 2 < n) ? __shfl(lns, j2) : 0.f;
            float w3 = (j + 3 < n) ? __shfl(lns, j3) : 0.f;
            float2 v0 = vb[(size_t)s0 * 64 + lane];
            float2 v1 = vb[(size_t)s1 * 64 + lane];
            float2 v2 = vb[(size_t)s2 * 64 + lane];
            float2 v3 = vb[(size_t)s3 * 64 + lane];
            accx += w0 * v0.x + w1 * v1.x + w2 * v2.x + w3 * v3.x;
            accy += w0 * v0.y + w1 * v1.y + w2 * v2.y + w3 * v3.y;
        }
    }
    float2 bb = *(const float2*)(b2 + lane * 2);
    float vx = dd * accx + bb.x;
    float vy = dd * accy + bb.y;
    float2 o;
    o.x = 1.0f / (1.0f + __expf(-vx));
    o.y = 1.0f / (1.0f + __expf(-vy));
    *(float2*)(out + (size_t)dst * LATD + lane * 2) = o;
}

// ============================================================================
// FUSED GEMM: t = relu(Ah @ W1T^T + b1) @ W2T^T  -- h never touches HBM.
// Per block: one 64-row M-slab. For each of 16 HID-chunks (128 cols):
//   phase 1: h_sub[64][128] via proven single-buffer BK=64 loop (As/Bs LDS),
//   epilogue: bias+relu -> hs LDS (fp16, 136-col stride: 16B-aligned rows,
//             <=4-way write banking),
//   phase 2: acc2 += hs @ W2T_chunk^T, W2T fragments read DIRECT from L2.
// LDS 41.4 KB -> 3 blocks/CU. W1T/W2T L2-resident (2.5 MB).
// ============================================================================
__global__ __launch_bounds__(256, 3) void k_fused(
    const _Float16* __restrict__ A,    // Ah [M_PAD][512]
    const _Float16* __restrict__ B1,   // W1T [2048][512]
    const float* __restrict__ b1,      // [2000] raw bias
    const _Float16* __restrict__ B2,   // W2T [128][2048]
    float* __restrict__ Cf)            // t [M_PAD][128]
{
    __shared__ __align__(16) _Float16 As[2 * 64 * 32];    //  8 KB [slice][64][32]
    __shared__ __align__(16) _Float16 Bs[2 * 128 * 32];   // 16 KB [slice][128][32]
    __shared__ __align__(16) _Float16 hs[64 * 136];       // 17 KB, stride 136

    const int tid = threadIdx.x;
    const int lane = tid & 63;
    const int w = tid >> 6;
    const int mBase = blockIdx.x * 64;

    const int srowA = w * 16 + (lane >> 2);
    const int srowB = w * 32 + (lane >> 2);
    const int scol = (lane & 3) * 8;
    const _Float16* Ag = A + (size_t)(mBase + srowA) * IND + scol;

    const int wm = (w & 1) * 32;     // phase1 rows / phase2 rows
    const int wn = (w >> 1) * 64;    // phase1 cols / phase2 lat cols
    const int lm = lane & 15;
    const int quad = lane >> 4;

    f32x4 acc2[2][4];
    #pragma unroll
    for (int i = 0; i < 2; ++i)
        #pragma unroll
        for (int j = 0; j < 4; ++j)
            acc2[i][j] = (f32x4){0.f, 0.f, 0.f, 0.f};

    #pragma unroll 1
    for (int nc = 0; nc < 16; ++nc) {
        // ---------- phase 1: h_sub = Ah_slab @ W1T[nc*128..+128]^T ----------
        f32x4 acc1[2][4];
        #pragma unroll
        for (int i = 0; i < 2; ++i)
            #pragma unroll
            for (int j = 0; j < 4; ++j)
                acc1[i][j] = (f32x4){0.f, 0.f, 0.f, 0.f};

        const _Float16* Bg0 = B1 + (size_t)(nc * 128 + srowB) * IND + scol;
        const _Float16* Bg1 = Bg0 + (size_t)16 * IND;

        for (int k0 = 0; k0 < IND; k0 += 64) {
            #pragma unroll
            for (int s = 0; s < 2; ++s) {
                gload_lds16(Ag + k0 + s * 32, As + s * 2048 + w * 512);
                gload_lds16(Bg0 + k0 + s * 32, Bs + s * 4096 + w * 1024);
                gload_lds16(Bg1 + k0 + s * 32, Bs + s * 4096 + w * 1024 + 512);
            }
            __syncthreads();
            #pragma unroll
            for (int s = 0; s < 2; ++s) {
                f16x8 af[2], bfr[4];
                #pragma unroll
                for (int mi = 0; mi < 2; ++mi)
                    af[mi] = *(const f16x8*)&As[s * 2048 + (wm + mi * 16 + lm) * 32 + quad * 8];
                #pragma unroll
                for (int ni = 0; ni < 4; ++ni)
                    bfr[ni] = *(const f16x8*)&Bs[s * 4096 + (wn + ni * 16 + lm) * 32 + quad * 8];
                #pragma unroll
                for (int mi = 0; mi < 2; ++mi)
                    #pragma unroll
                    for (int ni = 0; ni < 4; ++ni)
                        acc1[mi][ni] = __builtin_amdgcn_mfma_f32_16x16x32_f16(
                            af[mi], bfr[ni], acc1[mi][ni], 0, 0, 0);
            }
            __syncthreads();
        }

        // ---------- epilogue: bias + relu -> hs (fp16) ----------
        #pragma unroll
        for (int mi = 0; mi < 2; ++mi) {
            #pragma unroll
            for (int ni = 0; ni < 4; ++ni) {
                int col = wn + ni * 16 + lm;
                int gcol = nc * 128 + col;
                float bval = (gcol < HIDD) ? b1[gcol] : 0.f;
                #pragma unroll
                for (int r = 0; r < 4; ++r) {
                    int row = wm + mi * 16 + quad * 4 + r;
                    hs[row * 136 + col] = (_Float16)fmaxf(acc1[mi][ni][r] + bval, 0.f);
                }
            }
        }
        __syncthreads();

        // ---------- phase 2: acc2 += hs @ W2T[:, nc*128..+128]^T ----------
        #pragma unroll
        for (int ks = 0; ks < 4; ++ks) {
            f16x8 a2[2], b2f[4];
            #pragma unroll
            for (int mi = 0; mi < 2; ++mi)
                a2[mi] = *(const f16x8*)&hs[(wm + mi * 16 + lm) * 136 + ks * 32 + quad * 8];
            #pragma unroll
            for (int ni = 0; ni < 4; ++ni)
                b2f[ni] = *(const f16x8*)(B2 + (size_t)(wn + ni * 16 + lm) * N1_PAD
                                          + nc * 128 + ks * 32 + quad * 8);
            #pragma unroll
            for (int mi = 0; mi < 2; ++mi)
                #pragma unroll
                for (int ni = 0; ni < 4; ++ni)
                    acc2[mi][ni] = __builtin_amdgcn_mfma_f32_16x16x32_f16(
                        a2[mi], b2f[ni], acc2[mi][ni], 0, 0, 0);
        }
        // no barrier needed: next chunk's hs writes are ordered behind the
        // 16 k0-loop barriers that precede them.
    }

    // ---------- write t (f32) ----------
    #pragma unroll
    for (int mi = 0; mi < 2; ++mi) {
        #pragma unroll
        for (int ni = 0; ni < 4; ++ni) {
            int col = wn + ni * 16 + lm;
            #pragma unroll
            for (int r = 0; r < 4; ++r) {
                int rowg = mBase + wm + mi * 16 + quad * 4 + r;
                Cf[(size_t)rowg * LATD + col] = acc2[mi][ni][r];
            }
        }
    }
}

extern "C" void kernel_launch(void* const* d_in, const int* in_sizes, int n_in,
                              void* d_out, int out_size, void* d_ws, size_t ws_size,
                              hipStream_t stream) {
    const float* x  = (const float*)d_in[0];
    const int* ei   = (const int*)d_in[1];
    const float* W1 = (const float*)d_in[2];
    const float* b1 = (const float*)d_in[3];
    const float* W2 = (const float*)d_in[4];
    const float* b2 = (const float*)d_in[5];
    float* out = (float*)d_out;

    char* p = (char*)d_ws;
    auto alloc = [&](size_t bytes) {
        char* q = p; p += (bytes + 255) & ~(size_t)255; return q;
    };
    int* deg        = (int*)alloc((size_t)NN * 4);
    int* bsum       = (int*)alloc((size_t)NBLK * 4);
    int* row_ptr    = (int*)alloc((size_t)(NN + 1) * 4);
    int* cursor     = (int*)alloc((size_t)NN * 4);
    int* csr_src    = (int*)alloc((size_t)NE * 4);
    float* dis      = (float*)alloc((size_t)NN * 4);
    _Float16* W1T   = (_Float16*)alloc((size_t)N1_PAD * IND * 2);   // [2048][512]
    _Float16* W2T   = (_Float16*)alloc((size_t)LATD * N1_PAD * 2);  // [128][2048]
    _Float16* xh    = (_Float16*)alloc((size_t)NN * IND * 2);
    _Float16* Ah    = (_Float16*)alloc((size_t)M_PAD * IND * 2);
    float* t        = (float*)alloc((size_t)M_PAD * LATD * 4);

    hipMemsetAsync(deg,    0, (size_t)NN * 4, stream);
    hipMemsetAsync(cursor, 0, (size_t)NN * 4, stream);

    k_degree<<<(NE + 255) / 256, 256, 0, stream>>>(ei + NE, deg);
    k_bsum<<<NBLK, 256, 0, stream>>>(deg, bsum);
    k_bscan<<<1, 256, 0, stream>>>(bsum);
    k_scan_final<<<NBLK, 256, 0, stream>>>(deg, bsum, row_ptr, dis);
    k_fill<<<(NE + 255) / 256, 256, 0, stream>>>(ei, row_ptr, cursor, csr_src);

    {
        // W1 [512][2000] -> W1T [2048][512], pad cols zero-filled (no memset)
        dim3 gt1(N1_PAD / 32, IND / 32);
        k_transpose_tiled<<<gt1, 256, 0, stream>>>(W1, W1T, IND, HIDD, IND, IND, N1_PAD);
        // W2 [2000][128] -> W2T [128][2048], pad rows zero-filled (no memset)
        dim3 gt2(LATD / 32, N1_PAD / 32);
        k_transpose_tiled<<<gt2, 256, 0, stream>>>(W2, W2T, HIDD, LATD, N1_PAD, N1_PAD, LATD);
        k_xcvt<<<(NN * IND / 8 + 255) / 256, 256, 0, stream>>>(x, xh, NN * IND / 8);
    }

    k_gather_x<<<(NN + 3) / 4, 256, 0, stream>>>(xh, row_ptr, csr_src, dis, Ah);

    k_fused<<<M_PAD / 64, 256, 0, stream>>>(Ah, W1T, b1, W2T, t);

    k_gather_t<<<(NN + 3) / 4, 256, 0, stream>>>(t, row_ptr, csr_src, dis, b2, out);
}

// Round 7
// 500.602 us; speedup vs baseline: 1.2805x; 1.2805x over previous
//
#include <hip/hip_runtime.h>
#include <hip/hip_fp16.h>

#define NN 50000
#define NE 200000
#define IND 512
#define HIDD 2000
#define LATD 128

#define M_PAD 50176    // 392*128 = 784*64
#define N1_PAD 2048    // HIDD padded (pad cols forced to exact 0)
#define NBLK 196       // ceil(NN/256)

typedef _Float16 f16x8 __attribute__((ext_vector_type(8)));
typedef _Float16 f16x2 __attribute__((ext_vector_type(2)));
typedef float f32x4 __attribute__((ext_vector_type(4)));

__device__ __forceinline__ void gload_lds16(const _Float16* g, _Float16* l) {
    __builtin_amdgcn_global_load_lds(
        (const __attribute__((address_space(1))) unsigned int*)g,
        (__attribute__((address_space(3))) unsigned int*)l,
        16, 0, 0);
}

// ---- in-degree (int): deg[col[e]] += 1 ----
__global__ void k_degree(const int* __restrict__ col, int* __restrict__ deg) {
    int e = blockIdx.x * 256 + threadIdx.x;
    if (e < NE) atomicAdd(&deg[col[e]], 1);
}

// ---- hierarchical exclusive scan: (1) per-block sums ----
__global__ void k_bsum(const int* __restrict__ deg, int* __restrict__ bsum) {
    __shared__ int sm[4];
    int i = blockIdx.x * 256 + threadIdx.x;
    int v = (i < NN) ? deg[i] : 0;
    #pragma unroll
    for (int off = 32; off; off >>= 1) v += __shfl_down(v, off, 64);
    if ((threadIdx.x & 63) == 0) sm[threadIdx.x >> 6] = v;
    __syncthreads();
    if (threadIdx.x == 0) bsum[blockIdx.x] = sm[0] + sm[1] + sm[2] + sm[3];
}

// ---- (2) exclusive scan of the 196 block sums (one block) ----
__global__ void k_bscan(int* __restrict__ bsum) {
    __shared__ int sm[256];
    int tid = threadIdx.x;
    int v = (tid < NBLK) ? bsum[tid] : 0;
    sm[tid] = v;
    __syncthreads();
    #pragma unroll
    for (int off = 1; off < 256; off <<= 1) {
        int t = (tid >= off) ? sm[tid - off] : 0;
        __syncthreads();
        sm[tid] += t;
        __syncthreads();
    }
    if (tid < NBLK) bsum[tid] = sm[tid] - v;   // exclusive
}

// ---- (3) per-block exclusive scan + offset -> row_ptr; also dis = rsqrt(deg+1) ----
__global__ void k_scan_final(const int* __restrict__ deg, const int* __restrict__ bsum,
                             int* __restrict__ row_ptr, float* __restrict__ dis) {
    __shared__ int sm[256];
    int b = blockIdx.x, tid = threadIdx.x;
    int i = b * 256 + tid;
    int v = (i < NN) ? deg[i] : 0;
    if (i < NN) dis[i] = rsqrtf((float)v + 1.0f);
    sm[tid] = v;
    __syncthreads();
    #pragma unroll
    for (int off = 1; off < 256; off <<= 1) {
        int t = (tid >= off) ? sm[tid - off] : 0;
        __syncthreads();
        sm[tid] += t;
        __syncthreads();
    }
    if (i < NN) row_ptr[i] = bsum[b] + sm[tid] - v;
    if (i == NN - 1) row_ptr[NN] = bsum[b] + sm[tid];
}

// ---- fill CSR: csr_src[row_ptr[c] + cursor[c]++] = r ----
__global__ void k_fill(const int* __restrict__ ei, const int* __restrict__ row_ptr,
                       int* __restrict__ cursor, int* __restrict__ csr_src) {
    int e = blockIdx.x * 256 + threadIdx.x;
    if (e < NE) {
        int r = ei[e], c = ei[NE + e];
        int pos = atomicAdd(&cursor[c], 1);
        csr_src[row_ptr[c] + pos] = r;
    }
}

// ---- LDS-tiled transpose+convert: in f32 [R][C] -> out fp16, out[c*ldo + r].
//      Writes the FULL padded range, zero-filling pads (no separate memset). ----
__global__ void k_transpose_tiled(const float* __restrict__ in,
                                  _Float16* __restrict__ out, int R, int C, int ldo,
                                  int Rpad, int Cpad) {
    __shared__ float sm[32][33];
    int c0 = blockIdx.x * 32, r0 = blockIdx.y * 32;
    int tx = threadIdx.x & 31, ty = threadIdx.x >> 5;   // 32 x 8
    #pragma unroll
    for (int i = 0; i < 4; ++i) {
        int r = r0 + ty + i * 8, c = c0 + tx;
        sm[ty + i * 8][tx] = (r < R && c < C) ? in[(size_t)r * C + c] : 0.f;
    }
    __syncthreads();
    #pragma unroll
    for (int i = 0; i < 4; ++i) {
        int c = c0 + ty + i * 8, r = r0 + tx;
        if (c < Cpad && r < Rpad) out[(size_t)c * ldo + r] = (_Float16)sm[tx][ty + i * 8];
    }
}

// ---- x f32 -> xh fp16 (8 elems/thread) ----
__global__ void k_xcvt(const float* __restrict__ in, _Float16* __restrict__ out, int n8) {
    int i = blockIdx.x * 256 + threadIdx.x;
    if (i < n8) {
        float4 a = ((const float4*)in)[i * 2];
        float4 b = ((const float4*)in)[i * 2 + 1];
        f16x8 o;
        o[0] = (_Float16)a.x; o[1] = (_Float16)a.y; o[2] = (_Float16)a.z; o[3] = (_Float16)a.w;
        o[4] = (_Float16)b.x; o[5] = (_Float16)b.y; o[6] = (_Float16)b.z; o[7] = (_Float16)b.w;
        ((f16x8*)out)[i] = o;
    }
}

// ---- gather-aggregate x (fp16 src), 4-wide independent load slots ----
__global__ void k_gather_x(const _Float16* __restrict__ xh, const int* __restrict__ row_ptr,
                           const int* __restrict__ csr_src, const float* __restrict__ dis,
                           _Float16* __restrict__ Ah) {
    int dst = blockIdx.x * 4 + (threadIdx.x >> 6);
    if (dst >= NN) return;
    int lane = threadIdx.x & 63;
    float dd = dis[dst];
    const f16x8* vb = (const f16x8*)xh;                 // node stride 64 (512 halves / 8)
    f16x8 sv = vb[(size_t)dst * 64 + lane];
    float acc[8];
    #pragma unroll
    for (int q = 0; q < 8; ++q) acc[q] = dd * (float)sv[q];
    int beg = row_ptr[dst], end = row_ptr[dst + 1];
    for (int c = beg; c < end; c += 64) {
        int n = end - c; if (n > 64) n = 64;
        int li = (lane < n) ? csr_src[c + lane] : 0;    // lane-parallel idx load
        float lns = (lane < n) ? dis[li] : 0.f;         // lane-parallel dis gather
        for (int j = 0; j < n; j += 4) {
            int j1 = j + 1 < n ? j + 1 : n - 1;
            int j2 = j + 2 < n ? j + 2 : n - 1;
            int j3 = j + 3 < n ? j + 3 : n - 1;
            int s0 = __shfl(li, j),  s1 = __shfl(li, j1);
            int s2 = __shfl(li, j2), s3 = __shfl(li, j3);
            float w0 = __shfl(lns, j);
            float w1 = (j + 1 < n) ? __shfl(lns, j1) : 0.f;
            float w2 = (j + 2 < n) ? __shfl(lns, j2) : 0.f;
            float w3 = (j + 3 < n) ? __shfl(lns, j3) : 0.f;
            f16x8 v0 = vb[(size_t)s0 * 64 + lane];
            f16x8 v1 = vb[(size_t)s1 * 64 + lane];
            f16x8 v2 = vb[(size_t)s2 * 64 + lane];
            f16x8 v3 = vb[(size_t)s3 * 64 + lane];
            #pragma unroll
            for (int q = 0; q < 8; ++q)
                acc[q] += w0 * (float)v0[q] + w1 * (float)v1[q]
                        + w2 * (float)v2[q] + w3 * (float)v3[q];
        }
    }
    f16x8 o;
    #pragma unroll
    for (int q = 0; q < 8; ++q) o[q] = (_Float16)(dd * acc[q]);
    *(f16x8*)(Ah + (size_t)dst * IND + lane * 8) = o;
}

// ---- gather-aggregate t (fp16) + bias + sigmoid -> out (f32), 4-wide slots ----
__global__ void k_gather_t(const _Float16* __restrict__ t, const int* __restrict__ row_ptr,
                           const int* __restrict__ csr_src, const float* __restrict__ dis,
                           const float* __restrict__ b2, float* __restrict__ out) {
    int dst = blockIdx.x * 4 + (threadIdx.x >> 6);
    if (dst >= NN) return;
    int lane = threadIdx.x & 63;
    float dd = dis[dst];
    const f16x2* vb = (const f16x2*)t;                  // node stride 64 (128 halves / 2)
    f16x2 td = vb[(size_t)dst * 64 + lane];
    float accx = dd * (float)td[0], accy = dd * (float)td[1];
    int beg = row_ptr[dst], end = row_ptr[dst + 1];
    for (int c = beg; c < end; c += 64) {
        int n = end - c; if (n > 64) n = 64;
        int li = (lane < n) ? csr_src[c + lane] : 0;
        float lns = (lane < n) ? dis[li] : 0.f;
        for (int j = 0; j < n; j += 4) {
            int j1 = j + 1 < n ? j + 1 : n - 1;
            int j2 = j + 2 < n ? j + 2 : n - 1;
            int j3 = j + 3 < n ? j + 3 : n - 1;
            int s0 = __shfl(li, j),  s1 = __shfl(li, j1);
            int s2 = __shfl(li, j2), s3 = __shfl(li, j3);
            float w0 = __shfl(lns, j);
            float w1 = (j + 1 < n) ? __shfl(lns, j1) : 0.f;
            float w2 = (j + 2 < n) ? __shfl(lns, j2) : 0.f;
            float w3 = (j + 3 < n) ? __shfl(lns, j3) : 0.f;
            f16x2 v0 = vb[(size_t)s0 * 64 + lane];
            f16x2 v1 = vb[(size_t)s1 * 64 + lane];
            f16x2 v2 = vb[(size_t)s2 * 64 + lane];
            f16x2 v3 = vb[(size_t)s3 * 64 + lane];
            accx += w0 * (float)v0[0] + w1 * (float)v1[0]
                  + w2 * (float)v2[0] + w3 * (float)v3[0];
            accy += w0 * (float)v0[1] + w1 * (float)v1[1]
                  + w2 * (float)v2[1] + w3 * (float)v3[1];
        }
    }
    float2 bb = *(const float2*)(b2 + lane * 2);
    float vx = dd * accx + bb.x;
    float vy = dd * accy + bb.y;
    float2 o;
    o.x = 1.0f / (1.0f + __expf(-vx));
    o.y = 1.0f / (1.0f + __expf(-vy));
    *(float2*)(out + (size_t)dst * LATD + lane * 2) = o;
}

// ---- GEMM1: h = relu(Ah @ W1T^T + b1), 128x128 tile, BK=64 (2x32 slices),
//      XCD swizzle, single-buffer (proven structure), split into 4 dispatches. ----
__global__ __launch_bounds__(256, 2) void k_gemm1(
    const _Float16* __restrict__ A,    // [M_PAD][512]
    const _Float16* __restrict__ Bt,   // [2048][512]
    const float* __restrict__ bias,    // [2000] raw b1
    _Float16* __restrict__ Ch,         // [M_PAD][2048]
    int mT0, int slab)
{
    const int b = blockIdx.x;
    const int mT = mT0 + (b & 7) * slab + ((b >> 3) >> 4);
    const int nT = (b >> 3) & 15;
    const int mBase = mT * 128;
    const int nBase = nT * 128;

    __shared__ __align__(16) _Float16 As[2 * 128 * 32];   // 16 KB: [slice][128][32]
    __shared__ __align__(16) _Float16 Bs[2 * 128 * 32];

    const int tid = threadIdx.x;
    const int lane = tid & 63;
    const int w = tid >> 6;

    const int srow = w * 32 + (lane >> 2);   // + (0|16) per chunk
    const int scol = (lane & 3) * 8;
    const _Float16* Ag0 = A + (size_t)(mBase + srow) * IND + scol;
    const _Float16* Ag1 = Ag0 + (size_t)16 * IND;
    const _Float16* Bg0 = Bt + (size_t)(nBase + srow) * IND + scol;
    const _Float16* Bg1 = Bg0 + (size_t)16 * IND;

    const int wm = (w >> 1) * 64;
    const int wn = (w & 1) * 64;
    const int lm = lane & 15;
    const int quad = lane >> 4;

    f32x4 acc[4][4];
    #pragma unroll
    for (int i = 0; i < 4; ++i)
        #pragma unroll
        for (int j = 0; j < 4; ++j)
            acc[i][j] = (f32x4){0.f, 0.f, 0.f, 0.f};

    for (int k0 = 0; k0 < IND; k0 += 64) {
        #pragma unroll
        for (int s = 0; s < 2; ++s) {
            gload_lds16(Ag0 + k0 + s * 32, As + s * 4096 + w * 1024);
            gload_lds16(Ag1 + k0 + s * 32, As + s * 4096 + w * 1024 + 512);
            gload_lds16(Bg0 + k0 + s * 32, Bs + s * 4096 + w * 1024);
            gload_lds16(Bg1 + k0 + s * 32, Bs + s * 4096 + w * 1024 + 512);
        }
        __syncthreads();

        #pragma unroll
        for (int s = 0; s < 2; ++s) {
            f16x8 af[4], bfr[4];
            #pragma unroll
            for (int mi = 0; mi < 4; ++mi)
                af[mi] = *(const f16x8*)&As[s * 4096 + (wm + mi * 16 + lm) * 32 + quad * 8];
            #pragma unroll
            for (int ni = 0; ni < 4; ++ni)
                bfr[ni] = *(const f16x8*)&Bs[s * 4096 + (wn + ni * 16 + lm) * 32 + quad * 8];
            #pragma unroll
            for (int mi = 0; mi < 4; ++mi)
                #pragma unroll
                for (int ni = 0; ni < 4; ++ni)
                    acc[mi][ni] = __builtin_amdgcn_mfma_f32_16x16x32_f16(
                        af[mi], bfr[ni], acc[mi][ni], 0, 0, 0);
        }
        __syncthreads();
    }

    #pragma unroll
    for (int mi = 0; mi < 4; ++mi) {
        #pragma unroll
        for (int ni = 0; ni < 4; ++ni) {
            int col = nBase + wn + ni * 16 + lm;
            float bval = (col < HIDD) ? bias[col] : 0.f;
            #pragma unroll
            for (int r = 0; r < 4; ++r) {
                int rowg = mBase + wm + mi * 16 + quad * 4 + r;
                float v = fmaxf(acc[mi][ni][r] + bval, 0.f);
                Ch[(size_t)rowg * N1_PAD + col] = (_Float16)v;
            }
        }
    }
}

// ---- GEMM2: t = h @ W2T^T  (fp16 out).
//      EXACT gemm1 structure: 128x128 tile, BK=64, single-buffer, 2 barriers/step.
//      K = 2048 (32 steps). Grid 392 = 8 XCD x 49 slabs -> fully resident. ----
__global__ __launch_bounds__(256, 2) void k_gemm2(
    const _Float16* __restrict__ A,    // h [M_PAD][2048]
    const _Float16* __restrict__ Bt,   // W2T [128][2048]
    _Float16* __restrict__ Cf)         // t fp16 [M_PAD][128]
{
    const int b = blockIdx.x;
    const int mT = (b & 7) * 49 + (b >> 3);   // XCD swizzle, 392 = 8*49 exact
    const int mBase = mT * 128;

    __shared__ __align__(16) _Float16 As[2 * 128 * 32];   // 16 KB
    __shared__ __align__(16) _Float16 Bs[2 * 128 * 32];   // 16 KB

    const int tid = threadIdx.x;
    const int lane = tid & 63;
    const int w = tid >> 6;

    const int srow = w * 32 + (lane >> 2);
    const int scol = (lane & 3) * 8;
    const _Float16* Ag0 = A + (size_t)(mBase + srow) * N1_PAD + scol;
    const _Float16* Ag1 = Ag0 + (size_t)16 * N1_PAD;
    const _Float16* Bg0 = Bt + (size_t)srow * N1_PAD + scol;   // 128 rows exactly
    const _Float16* Bg1 = Bg0 + (size_t)16 * N1_PAD;

    const int wm = (w >> 1) * 64;
    const int wn = (w & 1) * 64;
    const int lm = lane & 15;
    const int quad = lane >> 4;

    f32x4 acc[4][4];
    #pragma unroll
    for (int i = 0; i < 4; ++i)
        #pragma unroll
        for (int j = 0; j < 4; ++j)
            acc[i][j] = (f32x4){0.f, 0.f, 0.f, 0.f};

    for (int k0 = 0; k0 < N1_PAD; k0 += 64) {
        #pragma unroll
        for (int s = 0; s < 2; ++s) {
            gload_lds16(Ag0 + k0 + s * 32, As + s * 4096 + w * 1024);
            gload_lds16(Ag1 + k0 + s * 32, As + s * 4096 + w * 1024 + 512);
            gload_lds16(Bg0 + k0 + s * 32, Bs + s * 4096 + w * 1024);
            gload_lds16(Bg1 + k0 + s * 32, Bs + s * 4096 + w * 1024 + 512);
        }
        __syncthreads();

        #pragma unroll
        for (int s = 0; s < 2; ++s) {
            f16x8 af[4], bfr[4];
            #pragma unroll
            for (int mi = 0; mi < 4; ++mi)
                af[mi] = *(const f16x8*)&As[s * 4096 + (wm + mi * 16 + lm) * 32 + quad * 8];
            #pragma unroll
            for (int ni = 0; ni < 4; ++ni)
                bfr[ni] = *(const f16x8*)&Bs[s * 4096 + (wn + ni * 16 + lm) * 32 + quad * 8];
            #pragma unroll
            for (int mi = 0; mi < 4; ++mi)
                #pragma unroll
                for (int ni = 0; ni < 4; ++ni)
                    acc[mi][ni] = __builtin_amdgcn_mfma_f32_16x16x32_f16(
                        af[mi], bfr[ni], acc[mi][ni], 0, 0, 0);
        }
        __syncthreads();
    }

    #pragma unroll
    for (int mi = 0; mi < 4; ++mi) {
        #pragma unroll
        for (int ni = 0; ni < 4; ++ni) {
            int col = wn + ni * 16 + lm;
            #pragma unroll
            for (int r = 0; r < 4; ++r) {
                int rowg = mBase + wm + mi * 16 + quad * 4 + r;
                Cf[(size_t)rowg * LATD + col] = (_Float16)acc[mi][ni][r];
            }
        }
    }
}

extern "C" void kernel_launch(void* const* d_in, const int* in_sizes, int n_in,
                              void* d_out, int out_size, void* d_ws, size_t ws_size,
                              hipStream_t stream) {
    const float* x  = (const float*)d_in[0];
    const int* ei   = (const int*)d_in[1];
    const float* W1 = (const float*)d_in[2];
    const float* b1 = (const float*)d_in[3];
    const float* W2 = (const float*)d_in[4];
    const float* b2 = (const float*)d_in[5];
    float* out = (float*)d_out;

    char* p = (char*)d_ws;
    auto alloc = [&](size_t bytes) {
        char* q = p; p += (bytes + 255) & ~(size_t)255; return q;
    };
    int* deg        = (int*)alloc((size_t)NN * 4);
    int* bsum       = (int*)alloc((size_t)NBLK * 4);
    int* row_ptr    = (int*)alloc((size_t)(NN + 1) * 4);
    int* cursor     = (int*)alloc((size_t)NN * 4);
    int* csr_src    = (int*)alloc((size_t)NE * 4);
    float* dis      = (float*)alloc((size_t)NN * 4);
    _Float16* W1T   = (_Float16*)alloc((size_t)N1_PAD * IND * 2);   // [2048][512]
    _Float16* W2T   = (_Float16*)alloc((size_t)LATD * N1_PAD * 2);  // [128][2048]
    _Float16* xh    = (_Float16*)alloc((size_t)NN * IND * 2);
    _Float16* Ah    = (_Float16*)alloc((size_t)M_PAD * IND * 2);
    _Float16* h     = (_Float16*)alloc((size_t)M_PAD * N1_PAD * 2);
    _Float16* t     = (_Float16*)alloc((size_t)M_PAD * LATD * 2);

    hipMemsetAsync(deg,    0, (size_t)NN * 4, stream);
    hipMemsetAsync(cursor, 0, (size_t)NN * 4, stream);

    k_degree<<<(NE + 255) / 256, 256, 0, stream>>>(ei + NE, deg);
    k_bsum<<<NBLK, 256, 0, stream>>>(deg, bsum);
    k_bscan<<<1, 256, 0, stream>>>(bsum);
    k_scan_final<<<NBLK, 256, 0, stream>>>(deg, bsum, row_ptr, dis);
    k_fill<<<(NE + 255) / 256, 256, 0, stream>>>(ei, row_ptr, cursor, csr_src);

    {
        // W1 [512][2000] -> W1T [2048][512], pad cols zero-filled (no memset)
        dim3 gt1(N1_PAD / 32, IND / 32);
        k_transpose_tiled<<<gt1, 256, 0, stream>>>(W1, W1T, IND, HIDD, IND, IND, N1_PAD);
        // W2 [2000][128] -> W2T [128][2048], pad rows zero-filled (no memset)
        dim3 gt2(LATD / 32, N1_PAD / 32);
        k_transpose_tiled<<<gt2, 256, 0, stream>>>(W2, W2T, HIDD, LATD, N1_PAD, N1_PAD, LATD);
        k_xcvt<<<(NN * IND / 8 + 255) / 256, 256, 0, stream>>>(x, xh, NN * IND / 8);
    }

    k_gather_x<<<(NN + 3) / 4, 256, 0, stream>>>(xh, row_ptr, csr_src, dis, Ah);

    // gemm1 split 4 ways for profiler visibility: mT slabs 12/12/12/13 per XCD
    k_gemm1<<<8 * 12 * 16, 256, 0, stream>>>(Ah, W1T, b1, h, 0,   12);
    k_gemm1<<<8 * 12 * 16, 256, 0, stream>>>(Ah, W1T, b1, h, 96,  12);
    k_gemm1<<<8 * 12 * 16, 256, 0, stream>>>(Ah, W1T, b1, h, 192, 12);
    k_gemm1<<<8 * 13 * 16, 256, 0, stream>>>(Ah, W1T, b1, h, 288, 13);

    k_gemm2<<<392, 256, 0, stream>>>(h, W2T, t);

    k_gather_t<<<(NN + 3) / 4, 256, 0, stream>>>(t, row_ptr, csr_src, dis, b2, out);
}